// Round 1
// baseline (136.544 us; speedup 1.0000x reference)
//
#include <hip/hip_runtime.h>

// SparseNodeLinear: out[b,n,f] = sum_k (keep[n,k]*x[b,n,k]) * w[n,k,f] + bias[n,f]
// B=8, N=2048, K=N+1=2049, F=32. Pure HBM-bound: w=537MB dominates.

constexpr int NB = 8;     // batch
constexpr int NN = 2048;  // nodes
constexpr int NK = 2049;  // N+1
constexpr int NF = 32;    // out features

// MODE: 0 = mask stored as int32, 1 = as uint8 (numpy bool), 2 = as float32
template <int MODE>
__device__ __forceinline__ void kloop(const float* __restrict__ x,
                                      const float* __restrict__ wrow,
                                      const void* __restrict__ mask,
                                      int n, int fq, int klane,
                                      float acc[NB][4]) {
  const size_t xstride = (size_t)NN * NK;     // per-batch stride in x
  const float* xn = x + (size_t)n * NK;       // x[0, n, 0]
  const int mbase = n * NK;

  // k = t*128 + u*32 + klane, klane = ws*8+kk in [0,32)
  for (int t = 0; t < 17; ++t) {
    const int kb = t * 128 + klane;
    float4 wv[4];
    float sc[4];
    float xv[4][NB];
#pragma unroll
    for (int u = 0; u < 4; ++u) {
      const int ku = kb + u * 32;
      const int kc = (ku < NK) ? ku : (NK - 1);  // clamped for safe addressing
      const bool valid = (ku < NK);
      bool keep;
      if (MODE == 0)
        keep = (((const int*)mask)[mbase + kc] == 0);
      else if (MODE == 1)
        keep = (((const unsigned char*)mask)[mbase + kc] == 0);
      else
        keep = (((const float*)mask)[mbase + kc] == 0.0f);
      sc[u] = (valid && keep) ? 1.0f : 0.0f;
      // coalesced: wave's 64 lanes (8 kk x 8 fq) cover 1KB contiguous
      wv[u] = *(const float4*)(wrow + (size_t)kc * NF + fq * 4);
#pragma unroll
      for (int b = 0; b < NB; ++b)
        xv[u][b] = xn[(size_t)b * xstride + kc];
    }
#pragma unroll
    for (int u = 0; u < 4; ++u) {
      float4 wm;
      wm.x = wv[u].x * sc[u];
      wm.y = wv[u].y * sc[u];
      wm.z = wv[u].z * sc[u];
      wm.w = wv[u].w * sc[u];
#pragma unroll
      for (int b = 0; b < NB; ++b) {
        acc[b][0] = fmaf(xv[u][b], wm.x, acc[b][0]);
        acc[b][1] = fmaf(xv[u][b], wm.y, acc[b][1]);
        acc[b][2] = fmaf(xv[u][b], wm.z, acc[b][2]);
        acc[b][3] = fmaf(xv[u][b], wm.w, acc[b][3]);
      }
    }
  }
}

__global__ __launch_bounds__(256) void snl_kernel(
    const float* __restrict__ x, const float* __restrict__ w,
    const float* __restrict__ bias, const void* __restrict__ mask,
    float* __restrict__ out) {
  __shared__ float part[4][8][32];  // [wave][fq][b*4+j]
  __shared__ int smode;

  const int tid = threadIdx.x;
  const int n = blockIdx.x;

  // --- mask dtype detection (wave 0 sniffs first 256 bytes) ---
  // int32 mode: words are 0/1. uint8 mode: words are packed 0/1 bytes (>1 with
  // overwhelming probability among 64 words; avg degree 32/2048 -> masks ~=1).
  // float mode: words are 0x3F800000 / 0.
  if (tid < 64) {
    unsigned v = ((const unsigned*)mask)[tid];
    unsigned long long bf = __ballot((v >> 24) == 0x3Fu);
    unsigned long long bg = __ballot(v > 1u);
    if (tid == 0) smode = bf ? 2 : (bg ? 1 : 0);
  }
  __syncthreads();
  const int mode = smode;

  const int fq = tid & 7;         // f quad: f = 4*fq .. 4*fq+3
  const int kk = (tid >> 3) & 7;  // k offset within wave
  const int ws = tid >> 6;        // wave id
  const int klane = ws * 8 + kk;  // k offset within block's 32-k slice

  float acc[NB][4];
#pragma unroll
  for (int b = 0; b < NB; ++b)
#pragma unroll
    for (int j = 0; j < 4; ++j) acc[b][j] = 0.0f;

  const float* wrow = w + (size_t)n * NK * NF;

  if (mode == 1)
    kloop<1>(x, wrow, mask, n, fq, klane, acc);
  else if (mode == 0)
    kloop<0>(x, wrow, mask, n, fq, klane, acc);
  else
    kloop<2>(x, wrow, mask, n, fq, klane, acc);

  // --- reduce over k-splits ---
  // intra-wave butterfly over kk (lane bits 3..5)
#pragma unroll
  for (int m = 8; m <= 32; m <<= 1) {
#pragma unroll
    for (int b = 0; b < NB; ++b)
#pragma unroll
      for (int j = 0; j < 4; ++j)
        acc[b][j] += __shfl_xor(acc[b][j], m, 64);
  }
  // cross-wave via LDS: lanes 0..7 of each wave hold the wave-sum per fq
  if ((tid & 63) < 8) {
#pragma unroll
    for (int b = 0; b < NB; ++b)
#pragma unroll
      for (int j = 0; j < 4; ++j) part[ws][fq][b * 4 + j] = acc[b][j];
  }
  __syncthreads();

  if (tid < 64) {
    const int b = tid >> 3;
    const int f2 = tid & 7;
    float4 o = *(const float4*)(bias + n * NF + f2 * 4);
#pragma unroll
    for (int wsi = 0; wsi < 4; ++wsi) {
      const float4 p = *(const float4*)&part[wsi][f2][b * 4];
      o.x += p.x;
      o.y += p.y;
      o.z += p.z;
      o.w += p.w;
    }
    *(float4*)(out + ((size_t)b * NN + n) * NF + f2 * 4) = o;
  }
}

extern "C" void kernel_launch(void* const* d_in, const int* in_sizes, int n_in,
                              void* d_out, int out_size, void* d_ws,
                              size_t ws_size, hipStream_t stream) {
  const float* x = (const float*)d_in[0];
  const float* w = (const float*)d_in[1];
  const float* bias = (const float*)d_in[2];
  const void* mask = d_in[3];  // dtype sniffed on device
  float* out = (float*)d_out;

  hipLaunchKernelGGL(snl_kernel, dim3(NN), dim3(256), 0, stream, x, w, bias,
                     mask, out);
}

// Round 2
// 134.398 us; speedup vs baseline: 1.0160x; 1.0160x over previous
//
#include <hip/hip_runtime.h>

// SparseNodeLinear: out[b,n,f] = sum_k (keep[n,k]*x[b,n,k]) * w[n,k,f] + bias[n,f]
// B=8, N=2048, K=N+1=2049, F=32. HBM-bound: w=537MB read-once dominates.
// R1: LDS-stage x (pre-masked, double-buffered) -> w stream is the only hot
// global traffic; x read exactly once, coalesced.

constexpr int NB = 8;
constexpr int NN = 2048;
constexpr int NK = 2049;
constexpr int NF = 32;
constexpr size_t XSTR = (size_t)NN * NK;  // per-batch stride in x

// mode: 0 = int32 mask, 1 = uint8 (numpy bool), 2 = float32
__device__ __forceinline__ float ld_scale(const void* __restrict__ mask,
                                          size_t idx, int mode) {
  bool drop;
  if (mode == 0)
    drop = ((const int*)mask)[idx] != 0;
  else if (mode == 1)
    drop = ((const unsigned char*)mask)[idx] != 0;
  else
    drop = ((const float*)mask)[idx] != 0.0f;
  return drop ? 0.0f : 1.0f;  // keep where mask==0 (masked_fill semantics)
}

__global__ __launch_bounds__(256) void snl_kernel(
    const float* __restrict__ x, const float* __restrict__ w,
    const float* __restrict__ bias, const void* __restrict__ mask,
    float* __restrict__ out) {
  __shared__ float xs[2][NB][128];   // double-buffered pre-masked x tile (8KB)
  __shared__ float part[4][8][32];   // cross-wave reduce [wave][fq][b*4+j]
  __shared__ int smode;

  const int tid = threadIdx.x;
  const int n = blockIdx.x;

  // --- mask dtype sniff (wave 0, first 256 bytes) ---
  if (tid < 64) {
    unsigned v = ((const unsigned*)mask)[tid];
    unsigned long long bf = __ballot((v >> 24) == 0x3Fu);  // float 1.0f pattern
    unsigned long long bg = __ballot(v > 1u);              // packed bytes
    if (tid == 0) smode = bf ? 2 : (bg ? 1 : 0);
  }
  __syncthreads();
  const int mode = smode;

  // compute-phase lane mapping: wave covers 8 k x 32 f (1KB contiguous w)
  const int fq = tid & 7;          // f-quad
  const int kk = (tid >> 3) & 7;   // k within wave slice
  const int ws = tid >> 6;         // wave id
  const int klane = ws * 8 + kk;   // k in [0,32) per u-step

  // stage-phase mapping: 256 threads cover 128 k x 8 b (4 loads each)
  const int sk = tid & 127;
  const int sh = tid >> 7;  // b base = 4*sh

  const float* xn = x + (size_t)n * NK;
  const float* wrow = w + (size_t)n * NK * NF;
  const size_t mbase = (size_t)n * NK;

  float acc[NB][4];
#pragma unroll
  for (int b = 0; b < NB; ++b)
#pragma unroll
    for (int j = 0; j < 4; ++j) acc[b][j] = 0.0f;

  // prologue: stage tile 0
  {
    const float sc = ld_scale(mask, mbase + sk, mode);
#pragma unroll
    for (int i = 0; i < 4; ++i)
      xs[0][sh * 4 + i][sk] = xn[(size_t)(sh * 4 + i) * XSTR + sk] * sc;
  }
  __syncthreads();

  for (int t = 0; t < 16; ++t) {
    const int cur = t & 1;
    const bool pf = (t + 1 < 16);
    float xr[4], scr = 0.0f;
    if (pf) {  // issue next-tile x loads early (latency hides under compute)
      const int kg = (t + 1) * 128 + sk;
      scr = ld_scale(mask, mbase + kg, mode);
#pragma unroll
      for (int i = 0; i < 4; ++i)
        xr[i] = xn[(size_t)(sh * 4 + i) * XSTR + kg];
    }

    const float* wt = wrow + (size_t)t * 128 * NF;
#pragma unroll
    for (int u = 0; u < 4; ++u) {
      const int kl = u * 32 + klane;
      const float4 wv = *(const float4*)(wt + (size_t)kl * NF + fq * 4);
#pragma unroll
      for (int b = 0; b < NB; ++b) {
        const float xv = xs[cur][b][kl];  // broadcast ds_read, conflict-free
        acc[b][0] = fmaf(xv, wv.x, acc[b][0]);
        acc[b][1] = fmaf(xv, wv.y, acc[b][1]);
        acc[b][2] = fmaf(xv, wv.z, acc[b][2]);
        acc[b][3] = fmaf(xv, wv.w, acc[b][3]);
      }
    }

    if (pf) {  // write staged tile after compute (T14 split)
#pragma unroll
      for (int i = 0; i < 4; ++i)
        xs[cur ^ 1][sh * 4 + i][sk] = xr[i] * scr;
    }
    __syncthreads();
  }

  // --- reduce over k-splits: butterfly over kk bits (lane bits 3..5) ---
#pragma unroll
  for (int m = 8; m <= 32; m <<= 1) {
#pragma unroll
    for (int b = 0; b < NB; ++b)
#pragma unroll
      for (int j = 0; j < 4; ++j)
        acc[b][j] += __shfl_xor(acc[b][j], m, 64);
  }
  if ((tid & 63) < 8) {
#pragma unroll
    for (int b = 0; b < NB; ++b)
#pragma unroll
      for (int j = 0; j < 4; ++j) part[ws][fq][b * 4 + j] = acc[b][j];
  }
  __syncthreads();

  if (tid < 64) {
    const int b = tid >> 3;
    const int f2 = tid & 7;
    float4 o = *(const float4*)(bias + (size_t)n * NF + f2 * 4);
    // k=2048 tail (K = 16*128 + 1)
    {
      const float sc = ld_scale(mask, mbase + 2048, mode);
      const float xv = xn[(size_t)b * XSTR + 2048] * sc;
      const float4 wv = *(const float4*)(wrow + (size_t)2048 * NF + f2 * 4);
      o.x += xv * wv.x;
      o.y += xv * wv.y;
      o.z += xv * wv.z;
      o.w += xv * wv.w;
    }
#pragma unroll
    for (int wsi = 0; wsi < 4; ++wsi) {
      const float4 p = *(const float4*)&part[wsi][f2][b * 4];
      o.x += p.x;
      o.y += p.y;
      o.z += p.z;
      o.w += p.w;
    }
    *(float4*)(out + ((size_t)b * NN + n) * NF + f2 * 4) = o;
  }
}

extern "C" void kernel_launch(void* const* d_in, const int* in_sizes, int n_in,
                              void* d_out, int out_size, void* d_ws,
                              size_t ws_size, hipStream_t stream) {
  const float* x = (const float*)d_in[0];
  const float* w = (const float*)d_in[1];
  const float* bias = (const float*)d_in[2];
  const void* mask = d_in[3];  // dtype sniffed on device
  float* out = (float*)d_out;

  hipLaunchKernelGGL(snl_kernel, dim3(NN), dim3(256), 0, stream, x, w, bias,
                     mask, out);
}

// Round 3
// 121.927 us; speedup vs baseline: 1.1199x; 1.1023x over previous
//
#include <hip/hip_runtime.h>

// SparseNodeLinear: out[b,n,f] = sum_k (keep[n,k]*x[b,n,k]) * w[n,k,f] + bias[n,f]
// B=8, N=2048, K=N+1=2049, F=32. HBM-bound: w=537MB read-once dominates.
// R2: per-wave CONTIGUOUS k-ownership (8KB sequential w runs per wave per tile),
// 8 w-loads in flight, BK=256 (8 barriers), nontemporal w/x loads.

constexpr int NB = 8;
constexpr int NN = 2048;
constexpr int NK = 2049;
constexpr int NF = 32;
constexpr int BK = 256;
constexpr int NTL = 8;  // 8*256 = 2048, k=2048 tail in epilogue
constexpr size_t XSTR = (size_t)NN * NK;

using f4 = __attribute__((ext_vector_type(4))) float;

// mode: 0 = int32 mask, 1 = uint8 (numpy bool), 2 = float32
__device__ __forceinline__ float ld_scale(const void* __restrict__ mask,
                                          size_t idx, int mode) {
  bool drop;
  if (mode == 0)
    drop = ((const int*)mask)[idx] != 0;
  else if (mode == 1)
    drop = ((const unsigned char*)mask)[idx] != 0;
  else
    drop = ((const float*)mask)[idx] != 0.0f;
  return drop ? 0.0f : 1.0f;  // keep where mask==0
}

__global__ __launch_bounds__(256) void snl_kernel(
    const float* __restrict__ x, const float* __restrict__ w,
    const float* __restrict__ bias, const void* __restrict__ mask,
    float* __restrict__ out) {
  __shared__ float xs[2][NB][BK];  // double-buffered pre-masked x tile (16KB)
  __shared__ float part[4][8][32];
  __shared__ int smode;

  const int tid = threadIdx.x;
  const int n = blockIdx.x;

  // --- mask dtype sniff ---
  if (tid < 64) {
    unsigned v = ((const unsigned*)mask)[tid];
    unsigned long long bf = __ballot((v >> 24) == 0x3Fu);
    unsigned long long bg = __ballot(v > 1u);
    if (tid == 0) smode = bf ? 2 : (bg ? 1 : 0);
  }
  __syncthreads();
  const int mode = smode;

  const int fq = tid & 7;         // f-quad
  const int kk = (tid >> 3) & 7;  // k within 8-wide slice
  const int ws = tid >> 6;        // wave id: owns k [ws*64, ws*64+64) per tile
  const int lane = tid & 63;
  const int skl = ws * 64 + lane;  // stage k index 0..255 (wave-contiguous)

  const float* xn = x + (size_t)n * NK;
  const float* wrow = w + (size_t)n * NK * NF;
  const size_t mbase = (size_t)n * NK;

  float acc[NB][4];
#pragma unroll
  for (int b = 0; b < NB; ++b)
#pragma unroll
    for (int j = 0; j < 4; ++j) acc[b][j] = 0.0f;

  // prologue: stage tile 0
  {
    const float sc = ld_scale(mask, mbase + skl, mode);
#pragma unroll
    for (int i = 0; i < NB; ++i)
      xs[0][i][skl] =
          __builtin_nontemporal_load(&xn[(size_t)i * XSTR + skl]) * sc;
  }
  __syncthreads();

  for (int t = 0; t < NTL; ++t) {
    const int cur = t & 1;
    const bool pf = (t + 1 < NTL);
    float xr[NB], scr = 0.0f;
    if (pf) {
      const int kg = (t + 1) * BK + skl;
      scr = ld_scale(mask, mbase + kg, mode);
#pragma unroll
      for (int i = 0; i < NB; ++i)
        xr[i] = __builtin_nontemporal_load(&xn[(size_t)i * XSTR + kg]);
    }

    // wave ws streams 8KB contiguous: k = t*256 + ws*64 + u*8 + kk, u=0..7
    const float* wt = wrow + (size_t)t * BK * NF + (size_t)ws * 64 * NF;
    f4 wv[8];
#pragma unroll
    for (int u = 0; u < 8; ++u)
      wv[u] = __builtin_nontemporal_load(
          (const f4*)(wt + (size_t)(u * 8 + kk) * NF + fq * 4));

#pragma unroll
    for (int u = 0; u < 8; ++u) {
      const int kl = ws * 64 + u * 8 + kk;
#pragma unroll
      for (int b = 0; b < NB; ++b) {
        const float xv = xs[cur][b][kl];  // 8 distinct banks + broadcast: free
        acc[b][0] = fmaf(xv, wv[u][0], acc[b][0]);
        acc[b][1] = fmaf(xv, wv[u][1], acc[b][1]);
        acc[b][2] = fmaf(xv, wv[u][2], acc[b][2]);
        acc[b][3] = fmaf(xv, wv[u][3], acc[b][3]);
      }
    }

    if (pf) {
#pragma unroll
      for (int i = 0; i < NB; ++i) xs[cur ^ 1][i][skl] = xr[i] * scr;
    }
    __syncthreads();
  }

  // --- reduce over kk bits (lane bits 3..5), then cross-wave ---
#pragma unroll
  for (int m = 8; m <= 32; m <<= 1) {
#pragma unroll
    for (int b = 0; b < NB; ++b)
#pragma unroll
      for (int j = 0; j < 4; ++j)
        acc[b][j] += __shfl_xor(acc[b][j], m, 64);
  }
  if (lane < 8) {
#pragma unroll
    for (int b = 0; b < NB; ++b)
#pragma unroll
      for (int j = 0; j < 4; ++j) part[ws][fq][b * 4 + j] = acc[b][j];
  }
  __syncthreads();

  if (tid < 64) {
    const int b = tid >> 3;
    const int f2 = tid & 7;
    f4 o = *(const f4*)(bias + (size_t)n * NF + f2 * 4);
    // k=2048 tail
    {
      const float sc = ld_scale(mask, mbase + 2048, mode);
      const float xv = xn[(size_t)b * XSTR + 2048] * sc;
      const f4 wv = *(const f4*)(wrow + (size_t)2048 * NF + f2 * 4);
      o += xv * wv;
    }
#pragma unroll
    for (int wsi = 0; wsi < 4; ++wsi) {
      const f4 p = *(const f4*)&part[wsi][f2][b * 4];
      o += p;
    }
    *(f4*)(out + ((size_t)b * NN + n) * NF + f2 * 4) = o;
  }
}

extern "C" void kernel_launch(void* const* d_in, const int* in_sizes, int n_in,
                              void* d_out, int out_size, void* d_ws,
                              size_t ws_size, hipStream_t stream) {
  const float* x = (const float*)d_in[0];
  const float* w = (const float*)d_in[1];
  const float* bias = (const float*)d_in[2];
  const void* mask = d_in[3];  // dtype sniffed on device
  float* out = (float*)d_out;

  hipLaunchKernelGGL(snl_kernel, dim3(NN), dim3(256), 0, stream, x, w, bias,
                     mask, out);
}